// Round 14
// baseline (510.927 us; speedup 1.0000x reference)
//
#include <hip/hip_runtime.h>
#include <hip/hip_fp16.h>
#include <hip/hip_cooperative_groups.h>

namespace cg = cooperative_groups;

#define N_NODES  20000
#define N_EDGES  320000
#define N_GRAPHS 128

typedef _Float16 half8 __attribute__((ext_vector_type(8)));
typedef float    f32x4 __attribute__((ext_vector_type(4)));

// ---------- cooperative prologue: zero | transpose | gstart | x->h ; hist ;
// ---------- scan ; scatter — one kernel, grid.sync between phases ----------
__global__ void prologue(const float* __restrict__ W1, const float* __restrict__ W2,
                         __half* __restrict__ w1t, __half* __restrict__ w2t,
                         const int* __restrict__ gid, int* __restrict__ gstart,
                         const float* __restrict__ x, __half* __restrict__ xh,
                         const int* __restrict__ src, const int* __restrict__ dst,
                         int* __restrict__ deg, int* __restrict__ cursor,
                         int* __restrict__ rowptr, int* __restrict__ esrc) {
    cg::grid_group grid = cg::this_grid();
    const int tid  = blockIdx.x * blockDim.x + threadIdx.x;
    const int nthr = gridDim.x * blockDim.x;

    // ---- phase 0: independent prep ----
    for (int i = tid; i < N_NODES; i += nthr) { deg[i] = 0; cursor[i] = 0; }
    for (int i = tid; i < 256 * 512; i += nthr) {
        int r = i >> 9, c = i & 511;
        w1t[c * 256 + r] = __float2half(W1[i]);
    }
    for (int i = tid; i < 512 * 128; i += nthr) {
        int r = i >> 7, c = i & 127;
        w2t[c * 512 + r] = __float2half(W2[i]);
    }
    if (tid <= N_GRAPHS) {
        if (tid == N_GRAPHS) gstart[N_GRAPHS] = N_NODES;
        else {
            int lo = 0, hi = N_NODES;
            while (lo < hi) {
                int mid = (lo + hi) >> 1;
                if (gid[mid] < tid) lo = mid + 1; else hi = mid;
            }
            gstart[tid] = lo;
        }
    }
    for (int i = tid; i < N_NODES * 64; i += nthr) {   // x -> fp16, 4/thread
        float4 v = *reinterpret_cast<const float4*>(&x[(size_t)i * 4]);
        union { __half2 h2[2]; uint2 u; } pk;
        pk.h2[0] = __floats2half2_rn(v.x, v.y);
        pk.h2[1] = __floats2half2_rn(v.z, v.w);
        *reinterpret_cast<uint2*>(&xh[(size_t)i * 4]) = pk.u;
    }
    grid.sync();

    // ---- phase 1: degree histogram ----
    for (int e = tid; e < N_EDGES; e += nthr) atomicAdd(&deg[dst[e]], 1);
    grid.sync();

    // ---- phase 2: exclusive scan (block 0 only; small) ----
    if (blockIdx.x == 0) {
        __shared__ int partial[256];
        const int t = threadIdx.x;
        const int CH = (N_NODES + 255) / 256;      // 79
        const int base = t * CH;
        int local = 0;
        for (int i = 0; i < CH; ++i)
            if (base + i < N_NODES) local += deg[base + i];
        partial[t] = local;
        __syncthreads();
        for (int o = 1; o < 256; o <<= 1) {
            int v = (t >= o) ? partial[t - o] : 0;
            __syncthreads();
            partial[t] += v;
            __syncthreads();
        }
        int run = (t == 0) ? 0 : partial[t - 1];
        for (int i = 0; i < CH; ++i) {
            if (base + i <= N_NODES) rowptr[base + i] = run;
            if (base + i < N_NODES) run += deg[base + i];
        }
    }
    grid.sync();

    // ---- phase 3: scatter edges into CSR order ----
    for (int e = tid; e < N_EDGES; e += nthr) {
        int d = dst[e];
        int pos = rowptr[d] + atomicAdd(&cursor[d], 1);
        esrc[pos] = src[e];
    }
}

// ---------- MFMA fp16 GEMM + fused el/er ----------
template <int BM, int BN, int WM, int WN, int H, int D>
__global__ __launch_bounds__(256) void gemm_mfma(
        const __half* __restrict__ A, const __half* __restrict__ BT,
        __half* __restrict__ C, const float* __restrict__ al,
        const float* __restrict__ ar, float* __restrict__ el,
        float* __restrict__ er, int Mm, int Nn, int Kk) {
    constexpr int BK  = 32;
    constexpr int MFR = WM / 16, NFR = WN / 16;
    constexpr int WCOLS = BN / WN;
    __shared__ __align__(16) __half As[BM * BK];
    __shared__ __align__(16) __half Bs[BN * BK];
    const int tid  = threadIdx.x;
    const int w    = tid >> 6, lane = tid & 63;
    const int wr   = w / WCOLS, wc = w % WCOLS;
    const int brow = blockIdx.x * BM;
    const int bcol = blockIdx.y * BN;
    const int lr   = lane & 15;
    const int lk   = (lane >> 4) * 8;

    f32x4 acc[MFR][NFR] = {};

    for (int k0 = 0; k0 < Kk; k0 += BK) {
        for (int c = tid; c < BM * 4; c += 256) {
            int r = c >> 2, ko = (c & 3) * 8;
            int gr = brow + r; if (gr >= Mm) gr = Mm - 1;
            int off = (r * BK + ko) ^ ((r & 7) << 3);
            *reinterpret_cast<uint4*>(&As[off]) =
                *reinterpret_cast<const uint4*>(&A[(size_t)gr * Kk + k0 + ko]);
        }
        for (int c = tid; c < BN * 4; c += 256) {
            int r = c >> 2, ko = (c & 3) * 8;
            int off = (r * BK + ko) ^ ((r & 7) << 3);
            *reinterpret_cast<uint4*>(&Bs[off]) =
                *reinterpret_cast<const uint4*>(&BT[(size_t)(bcol + r) * Kk + k0 + ko]);
        }
        __syncthreads();
        half8 af[MFR], bf[NFR];
#pragma unroll
        for (int m = 0; m < MFR; ++m) {
            int r = wr * WM + m * 16 + lr;
            af[m] = *reinterpret_cast<const half8*>(&As[(r * BK + lk) ^ ((r & 7) << 3)]);
        }
#pragma unroll
        for (int n = 0; n < NFR; ++n) {
            int r = wc * WN + n * 16 + lr;
            bf[n] = *reinterpret_cast<const half8*>(&Bs[(r * BK + lk) ^ ((r & 7) << 3)]);
        }
#pragma unroll
        for (int m = 0; m < MFR; ++m)
#pragma unroll
            for (int n = 0; n < NFR; ++n)
                acc[m][n] = __builtin_amdgcn_mfma_f32_16x16x32_f16(af[m], bf[n], acc[m][n], 0, 0, 0);
        __syncthreads();
    }

#pragma unroll
    for (int m = 0; m < MFR; ++m) {
        int r0 = brow + wr * WM + m * 16 + ((lane >> 4) << 2);
#pragma unroll
        for (int n = 0; n < NFR; ++n) {
            int cc = bcol + wc * WN + n * 16 + lr;
#pragma unroll
            for (int g = 0; g < 4; ++g)
                if (r0 + g < Mm) C[(size_t)(r0 + g) * Nn + cc] = __float2half(acc[m][n][g]);
        }
    }
    const int h = (bcol + wc * WN) / D;
    float alv[NFR], arv[NFR];
#pragma unroll
    for (int n = 0; n < NFR; ++n) {
        alv[n] = al[bcol + wc * WN + n * 16 + lr];
        arv[n] = ar[bcol + wc * WN + n * 16 + lr];
    }
#pragma unroll
    for (int m = 0; m < MFR; ++m) {
#pragma unroll
        for (int g = 0; g < 4; ++g) {
            float pl = 0.f, pr = 0.f;
#pragma unroll
            for (int n = 0; n < NFR; ++n) {
                pl += acc[m][n][g] * alv[n];
                pr += acc[m][n][g] * arv[n];
            }
            pl += __shfl_xor(pl, 1); pl += __shfl_xor(pl, 2);
            pl += __shfl_xor(pl, 4); pl += __shfl_xor(pl, 8);
            pr += __shfl_xor(pr, 1); pr += __shfl_xor(pr, 2);
            pr += __shfl_xor(pr, 4); pr += __shfl_xor(pr, 8);
            int gr = brow + wr * WM + m * 16 + ((lane >> 4) << 2) + g;
            if (lr == 0 && gr < Mm) {
                if constexpr (WN == D) {
                    el[(size_t)gr * H + h] = pl;
                    er[(size_t)gr * H + h] = pr;
                } else {
                    atomicAdd(&el[(size_t)gr * H + h], pl);
                    atomicAdd(&er[(size_t)gr * H + h], pr);
                }
            }
        }
    }
}

// ---------- per-node aggregation: wave-per-node, inline edge weights -------
template <int F, int H, bool HOUT>
__global__ __launch_bounds__(256) void node_aggr_wave(
        const __half* __restrict__ feat, const float* __restrict__ el,
        const float* __restrict__ er, const int* __restrict__ rowptr,
        const int* __restrict__ esrc, const float* __restrict__ bias,
        void* __restrict__ rst_, int N) {
    constexpr int LPN = F / 8;
    constexpr int NPW = 64 / LPN;
    constexpr int D   = F / H;
    const int wid  = (blockIdx.x * blockDim.x + threadIdx.x) >> 6;
    const int lane = threadIdx.x & 63;
    const int n    = wid * NPW + lane / LPN;
    if (n >= N) return;
    const int col = (lane % LPN) * 8;
    const int h   = col / D;
    const float ern = er[(size_t)n * H + h];
    const int rs = rowptr[n], re = rowptr[n + 1];
    const __half* fq = feat + col;

    float acc[8] = {};
    float dsum = 0.f;
    int i = rs;
    for (; i + 4 <= re; i += 4) {
        int s0 = esrc[i], s1 = esrc[i + 1], s2 = esrc[i + 2], s3 = esrc[i + 3];
        float x0 = el[(size_t)s0 * H + h] + ern;
        float x1 = el[(size_t)s1 * H + h] + ern;
        float x2 = el[(size_t)s2 * H + h] + ern;
        float x3 = el[(size_t)s3 * H + h] + ern;
        x0 = (x0 > 0.f) ? x0 : 0.2f * x0;
        x1 = (x1 > 0.f) ? x1 : 0.2f * x1;
        x2 = (x2 > 0.f) ? x2 : 0.2f * x2;
        x3 = (x3 > 0.f) ? x3 : 0.2f * x3;
        float w0 = __expf(x0), w1 = __expf(x1), w2 = __expf(x2), w3 = __expf(x3);
        union { uint4 u; __half2 h2[4]; } r0, r1, r2, r3;
        r0.u = *reinterpret_cast<const uint4*>(fq + (size_t)s0 * F);
        r1.u = *reinterpret_cast<const uint4*>(fq + (size_t)s1 * F);
        r2.u = *reinterpret_cast<const uint4*>(fq + (size_t)s2 * F);
        r3.u = *reinterpret_cast<const uint4*>(fq + (size_t)s3 * F);
        dsum += (w0 + w1) + (w2 + w3);
#pragma unroll
        for (int k = 0; k < 4; ++k) {
            float2 f0 = __half22float2(r0.h2[k]);
            float2 f1 = __half22float2(r1.h2[k]);
            float2 f2 = __half22float2(r2.h2[k]);
            float2 f3 = __half22float2(r3.h2[k]);
            acc[2 * k]     += w0 * f0.x + w1 * f1.x + w2 * f2.x + w3 * f3.x;
            acc[2 * k + 1] += w0 * f0.y + w1 * f1.y + w2 * f2.y + w3 * f3.y;
        }
    }
    for (; i < re; ++i) {
        int s = esrc[i];
        float x = el[(size_t)s * H + h] + ern;
        x = (x > 0.f) ? x : 0.2f * x;
        float w = __expf(x);
        union { uint4 u; __half2 h2[4]; } r;
        r.u = *reinterpret_cast<const uint4*>(fq + (size_t)s * F);
        dsum += w;
#pragma unroll
        for (int k = 0; k < 4; ++k) {
            float2 f = __half22float2(r.h2[k]);
            acc[2 * k]     += w * f.x;
            acc[2 * k + 1] += w * f.y;
        }
    }
    float inv = (re > rs) ? 1.f / dsum : 0.f;
    float4 b0 = *reinterpret_cast<const float4*>(bias + col);
    float4 b1 = *reinterpret_cast<const float4*>(bias + col + 4);
    float o[8] = {acc[0] * inv + b0.x, acc[1] * inv + b0.y,
                  acc[2] * inv + b0.z, acc[3] * inv + b0.w,
                  acc[4] * inv + b1.x, acc[5] * inv + b1.y,
                  acc[6] * inv + b1.z, acc[7] * inv + b1.w};
    if constexpr (HOUT) {
        union { __half2 h2[4]; uint4 u; } pk;
        pk.h2[0] = __floats2half2_rn(o[0], o[1]);
        pk.h2[1] = __floats2half2_rn(o[2], o[3]);
        pk.h2[2] = __floats2half2_rn(o[4], o[5]);
        pk.h2[3] = __floats2half2_rn(o[6], o[7]);
        *reinterpret_cast<uint4*>((__half*)rst_ + (size_t)n * F + col) = pk.u;
    } else {
        float* op = (float*)rst_ + (size_t)n * F + col;
        *reinterpret_cast<float4*>(op)     = make_float4(o[0], o[1], o[2], o[3]);
        *reinterpret_cast<float4*>(op + 4) = make_float4(o[4], o[5], o[6], o[7]);
    }
}

// ---------- per-graph mean pooling (sorted gid -> segmented reduce) --------
__global__ __launch_bounds__(1024) void seg_pool_kernel(
        const float* __restrict__ h, const int* __restrict__ start,
        float* __restrict__ out, int D) {
    __shared__ float part[7][128];
    int g = blockIdx.x;
    int d = threadIdx.x & 127;
    int j = threadIdx.x >> 7;           // 0..7
    int s = start[g], e = start[g + 1];
    float acc = 0.f;
    for (int n = s + j; n < e; n += 8) acc += h[(size_t)n * D + d];
    if (j > 0) part[j - 1][d] = acc;
    __syncthreads();
    if (j == 0) {
#pragma unroll
        for (int k = 0; k < 7; ++k) acc += part[k][d];
        out[(size_t)g * D + d] = acc / fmaxf((float)(e - s), 1.f);
    }
}

extern "C" void kernel_launch(void* const* d_in, const int* in_sizes, int n_in,
                              void* d_out, int out_size, void* d_ws, size_t ws_size,
                              hipStream_t stream) {
    const float* x   = (const float*)d_in[0];
    const float* W1  = (const float*)d_in[1];
    const float* al1 = (const float*)d_in[2];
    const float* ar1 = (const float*)d_in[3];
    const float* b1  = (const float*)d_in[4];
    const float* W2  = (const float*)d_in[5];
    const float* al2 = (const float*)d_in[6];
    const float* ar2 = (const float*)d_in[7];
    const float* b2  = (const float*)d_in[8];
    const int* src   = (const int*)d_in[9];
    const int* dst   = (const int*)d_in[10];
    const int* gid   = (const int*)d_in[11];
    float* out = (float*)d_out;

    float* ws = (float*)d_ws;
    size_t off = 0;
    int* deg    = (int*)(ws + off); off += N_NODES;     // zeroed in prologue
    int* cursor = (int*)(ws + off); off += N_NODES;     // zeroed in prologue
    int* rowptr = (int*)(ws + off); off += N_NODES + 4;
    int* gstart = (int*)(ws + off); off += N_GRAPHS + 4;
    int* esrc   = (int*)(ws + off); off += N_EDGES;
    __half* xh     = (__half*)(ws + off); off += (size_t)N_NODES * 128;   // 256 halves
    __half* w1t    = (__half*)(ws + off); off += 512 * 256 / 2;
    __half* w2t    = (__half*)(ws + off); off += 128 * 512 / 2;
    __half* feat1h = (__half*)(ws + off); off += (size_t)N_NODES * 256;   // 512 halves
    float*  el1    = ws + off; off += (size_t)N_NODES * 8;
    float*  er1    = ws + off; off += (size_t)N_NODES * 8;
    __half* rst1h  = (__half*)(ws + off); off += (size_t)N_NODES * 256;   // 512 halves
    __half* feat2h = (__half*)(ws + off); off += (size_t)N_NODES * 64;    // 128 halves
    float*  el2    = ws + off; off += N_NODES;
    float*  er2    = ws + off; off += N_NODES;
    float*  rst2   = ws + off; off += (size_t)N_NODES * 128;

    // ---- cooperative prologue (zero | transpose | gstart | x->h ; hist ;
    //      scan ; scatter) ----
    {
        void* args[] = {
            (void*)&W1, (void*)&W2, (void*)&w1t, (void*)&w2t,
            (void*)&gid, (void*)&gstart, (void*)&x, (void*)&xh,
            (void*)&src, (void*)&dst, (void*)&deg, (void*)&cursor,
            (void*)&rowptr, (void*)&esrc
        };
        hipLaunchCooperativeKernel((void*)prologue, dim3(1024), dim3(256),
                                   args, 0, stream);
    }

    // ===== layer 1: H=8, D=64 =====
    dim3 g1((N_NODES + 127) / 128, 512 / 128);
    gemm_mfma<128, 128, 64, 64, 8, 64><<<g1, 256, 0, stream>>>(
        xh, w1t, feat1h, al1, ar1, el1, er1, N_NODES, 512, 256);
    node_aggr_wave<512, 8, true><<<(N_NODES * 64 + 255) / 256, 256, 0, stream>>>(
        feat1h, el1, er1, rowptr, esrc, b1, rst1h, N_NODES);

    // ===== layer 2: H=1, D=128; WN==D -> plain el/er stores =====
    dim3 g2((N_NODES + 63) / 64, 128 / 128);
    gemm_mfma<64, 128, 16, 128, 1, 128><<<g2, 256, 0, stream>>>(
        rst1h, w2t, feat2h, al2, ar2, el2, er2, N_NODES, 128, 512);
    node_aggr_wave<128, 1, false><<<(N_NODES * 16 + 255) / 256, 256, 0, stream>>>(
        feat2h, el2, er2, rowptr, esrc, b2, rst2, N_NODES);

    // ===== readout: per-graph mean (segmented, no atomics) =====
    seg_pool_kernel<<<N_GRAPHS, 1024, 0, stream>>>(rst2, gstart, out, 128);
}

// Round 15
// 181.797 us; speedup vs baseline: 2.8104x; 2.8104x over previous
//
#include <hip/hip_runtime.h>
#include <hip/hip_fp16.h>

#define N_NODES  20000
#define N_EDGES  320000
#define N_GRAPHS 128

typedef _Float16 half8 __attribute__((ext_vector_type(8)));
typedef float    f32x4 __attribute__((ext_vector_type(4)));

// ---------- setup (transposes + gstart) + degree histogram, one launch ----
// All pieces depend only on the deg/cursor memset; mutually independent.
__global__ void setup_hist(const float* __restrict__ W1, const float* __restrict__ W2,
                           __half* __restrict__ w1t, __half* __restrict__ w2t,
                           const int* __restrict__ gid, int* __restrict__ gstart,
                           const int* __restrict__ dst, int* __restrict__ deg) {
    const int tid  = blockIdx.x * blockDim.x + threadIdx.x;
    const int nthr = gridDim.x * blockDim.x;
    for (int i = tid; i < 256 * 512; i += nthr) {
        int r = i >> 9, c = i & 511;
        w1t[c * 256 + r] = __float2half(W1[i]);
    }
    for (int i = tid; i < 512 * 128; i += nthr) {
        int r = i >> 7, c = i & 127;
        w2t[c * 512 + r] = __float2half(W2[i]);
    }
    if (tid <= N_GRAPHS) {
        if (tid == N_GRAPHS) gstart[N_GRAPHS] = N_NODES;
        else {
            int lo = 0, hi = N_NODES;
            while (lo < hi) {
                int mid = (lo + hi) >> 1;
                if (gid[mid] < tid) lo = mid + 1; else hi = mid;
            }
            gstart[tid] = lo;
        }
    }
    for (int e = tid; e < N_EDGES; e += nthr) atomicAdd(&deg[dst[e]], 1);
}

// ---------- single-block exclusive scan deg -> rowptr ----------
__global__ void scan_kernel(const int* __restrict__ deg, int* __restrict__ rowptr, int n) {
    __shared__ int partial[1024];
    const int t = threadIdx.x;
    const int CH = (n + 1023) / 1024;
    const int base = t * CH;
    int local = 0;
    for (int i = 0; i < CH; ++i)
        if (base + i < n) local += deg[base + i];
    partial[t] = local;
    __syncthreads();
    for (int o = 1; o < 1024; o <<= 1) {
        int v = (t >= o) ? partial[t - o] : 0;
        __syncthreads();
        partial[t] += v;
        __syncthreads();
    }
    int run = (t == 0) ? 0 : partial[t - 1];
    for (int i = 0; i < CH; ++i) {
        if (base + i <= n) rowptr[base + i] = run;
        if (base + i < n) run += deg[base + i];
    }
}

// ---------- MFMA fp16 GEMM + fused el/er (device body) ----------
template <int BM, int BN, int WM, int WN, int H, int D, bool AF32>
__device__ __forceinline__ void gemm_body(
        int bx, int by,
        const void* __restrict__ A_, const __half* __restrict__ BT,
        __half* __restrict__ C, const float* __restrict__ al,
        const float* __restrict__ ar, float* __restrict__ el,
        float* __restrict__ er, int Mm, int Nn, int Kk) {
    constexpr int BK  = 32;
    constexpr int MFR = WM / 16, NFR = WN / 16;
    constexpr int WCOLS = BN / WN;
    __shared__ __align__(16) __half As[BM * BK];
    __shared__ __align__(16) __half Bs[BN * BK];
    const int tid  = threadIdx.x;
    const int w    = tid >> 6, lane = tid & 63;
    const int wr   = w / WCOLS, wc = w % WCOLS;
    const int brow = bx * BM;
    const int bcol = by * BN;
    const int lr   = lane & 15;
    const int lk   = (lane >> 4) * 8;

    f32x4 acc[MFR][NFR] = {};

    for (int k0 = 0; k0 < Kk; k0 += BK) {
        for (int c = tid; c < BM * 4; c += 256) {
            int r = c >> 2, ko = (c & 3) * 8;
            int gr = brow + r; if (gr >= Mm) gr = Mm - 1;
            int off = (r * BK + ko) ^ ((r & 7) << 3);
            if constexpr (AF32) {
                const float* ap = (const float*)A_ + (size_t)gr * Kk + k0 + ko;
                float4 v0 = *reinterpret_cast<const float4*>(ap);
                float4 v1 = *reinterpret_cast<const float4*>(ap + 4);
                union { __half2 h2[4]; uint4 u; } pk;
                pk.h2[0] = __floats2half2_rn(v0.x, v0.y);
                pk.h2[1] = __floats2half2_rn(v0.z, v0.w);
                pk.h2[2] = __floats2half2_rn(v1.x, v1.y);
                pk.h2[3] = __floats2half2_rn(v1.z, v1.w);
                *reinterpret_cast<uint4*>(&As[off]) = pk.u;
            } else {
                *reinterpret_cast<uint4*>(&As[off]) =
                    *reinterpret_cast<const uint4*>((const __half*)A_ + (size_t)gr * Kk + k0 + ko);
            }
        }
        for (int c = tid; c < BN * 4; c += 256) {
            int r = c >> 2, ko = (c & 3) * 8;
            int off = (r * BK + ko) ^ ((r & 7) << 3);
            *reinterpret_cast<uint4*>(&Bs[off]) =
                *reinterpret_cast<const uint4*>(&BT[(size_t)(bcol + r) * Kk + k0 + ko]);
        }
        __syncthreads();
        half8 af[MFR], bf[NFR];
#pragma unroll
        for (int m = 0; m < MFR; ++m) {
            int r = wr * WM + m * 16 + lr;
            af[m] = *reinterpret_cast<const half8*>(&As[(r * BK + lk) ^ ((r & 7) << 3)]);
        }
#pragma unroll
        for (int n = 0; n < NFR; ++n) {
            int r = wc * WN + n * 16 + lr;
            bf[n] = *reinterpret_cast<const half8*>(&Bs[(r * BK + lk) ^ ((r & 7) << 3)]);
        }
#pragma unroll
        for (int m = 0; m < MFR; ++m)
#pragma unroll
            for (int n = 0; n < NFR; ++n)
                acc[m][n] = __builtin_amdgcn_mfma_f32_16x16x32_f16(af[m], bf[n], acc[m][n], 0, 0, 0);
        __syncthreads();
    }

#pragma unroll
    for (int m = 0; m < MFR; ++m) {
        int r0 = brow + wr * WM + m * 16 + ((lane >> 4) << 2);
#pragma unroll
        for (int n = 0; n < NFR; ++n) {
            int cc = bcol + wc * WN + n * 16 + lr;
#pragma unroll
            for (int g = 0; g < 4; ++g)
                if (r0 + g < Mm) C[(size_t)(r0 + g) * Nn + cc] = __float2half(acc[m][n][g]);
        }
    }
    const int h = (bcol + wc * WN) / D;
    float alv[NFR], arv[NFR];
#pragma unroll
    for (int n = 0; n < NFR; ++n) {
        alv[n] = al[bcol + wc * WN + n * 16 + lr];
        arv[n] = ar[bcol + wc * WN + n * 16 + lr];
    }
#pragma unroll
    for (int m = 0; m < MFR; ++m) {
#pragma unroll
        for (int g = 0; g < 4; ++g) {
            float pl = 0.f, pr = 0.f;
#pragma unroll
            for (int n = 0; n < NFR; ++n) {
                pl += acc[m][n][g] * alv[n];
                pr += acc[m][n][g] * arv[n];
            }
            pl += __shfl_xor(pl, 1); pl += __shfl_xor(pl, 2);
            pl += __shfl_xor(pl, 4); pl += __shfl_xor(pl, 8);
            pr += __shfl_xor(pr, 1); pr += __shfl_xor(pr, 2);
            pr += __shfl_xor(pr, 4); pr += __shfl_xor(pr, 8);
            int gr = brow + wr * WM + m * 16 + ((lane >> 4) << 2) + g;
            if (lr == 0 && gr < Mm) {
                if constexpr (WN == D) {
                    el[(size_t)gr * H + h] = pl;
                    er[(size_t)gr * H + h] = pr;
                } else {
                    atomicAdd(&el[(size_t)gr * H + h], pl);
                    atomicAdd(&er[(size_t)gr * H + h], pr);
                }
            }
        }
    }
}

// plain GEMM kernel (layer 2)
template <int BM, int BN, int WM, int WN, int H, int D, bool AF32>
__global__ __launch_bounds__(256) void gemm_kernel(
        const void* __restrict__ A_, const __half* __restrict__ BT,
        __half* __restrict__ C, const float* __restrict__ al,
        const float* __restrict__ ar, float* __restrict__ el,
        float* __restrict__ er, int Mm, int Nn, int Kk) {
    gemm_body<BM, BN, WM, WN, H, D, AF32>(blockIdx.x, blockIdx.y, A_, BT, C,
                                          al, ar, el, er, Mm, Nn, Kk);
}

// fused GEMM (layer 1) + CSR scatter: blocks [0,nbGemm) do GEMM tiles,
// blocks [nbGemm, nbGemm+1250) scatter edges. Independent work, no sync.
template <int BM, int BN, int WM, int WN, int H, int D, bool AF32>
__global__ __launch_bounds__(256) void gemm_scatter_kernel(
        const void* __restrict__ A_, const __half* __restrict__ BT,
        __half* __restrict__ C, const float* __restrict__ al,
        const float* __restrict__ ar, float* __restrict__ el,
        float* __restrict__ er, int Mm, int Nn, int Kk, int gemmRows,
        const int* __restrict__ src, const int* __restrict__ dst,
        const int* __restrict__ rowptr, int* __restrict__ cursor,
        int* __restrict__ esrc) {
    const int nbGemm = gemmRows * (Nn / BN);
    if ((int)blockIdx.x < nbGemm) {
        gemm_body<BM, BN, WM, WN, H, D, AF32>(blockIdx.x % gemmRows, blockIdx.x / gemmRows,
                                              A_, BT, C, al, ar, el, er, Mm, Nn, Kk);
    } else {
        int e = (blockIdx.x - nbGemm) * blockDim.x + threadIdx.x;
        if (e < N_EDGES) {
            int d = dst[e];
            int pos = rowptr[d] + atomicAdd(&cursor[d], 1);
            esrc[pos] = src[e];
        }
    }
}

// ---------- per-node aggregation: wave-per-node, inline edge weights -------
template <int F, int H, bool HOUT>
__global__ __launch_bounds__(256) void node_aggr_wave(
        const __half* __restrict__ feat, const float* __restrict__ el,
        const float* __restrict__ er, const int* __restrict__ rowptr,
        const int* __restrict__ esrc, const float* __restrict__ bias,
        void* __restrict__ rst_, int N) {
    constexpr int LPN = F / 8;
    constexpr int NPW = 64 / LPN;
    constexpr int D   = F / H;
    const int wid  = (blockIdx.x * blockDim.x + threadIdx.x) >> 6;
    const int lane = threadIdx.x & 63;
    const int n    = wid * NPW + lane / LPN;
    if (n >= N) return;
    const int col = (lane % LPN) * 8;
    const int h   = col / D;
    const float ern = er[(size_t)n * H + h];
    const int rs = rowptr[n], re = rowptr[n + 1];
    const __half* fq = feat + col;

    float acc[8] = {};
    float dsum = 0.f;
    int i = rs;
    for (; i + 4 <= re; i += 4) {
        int s0 = esrc[i], s1 = esrc[i + 1], s2 = esrc[i + 2], s3 = esrc[i + 3];
        float x0 = el[(size_t)s0 * H + h] + ern;
        float x1 = el[(size_t)s1 * H + h] + ern;
        float x2 = el[(size_t)s2 * H + h] + ern;
        float x3 = el[(size_t)s3 * H + h] + ern;
        x0 = (x0 > 0.f) ? x0 : 0.2f * x0;
        x1 = (x1 > 0.f) ? x1 : 0.2f * x1;
        x2 = (x2 > 0.f) ? x2 : 0.2f * x2;
        x3 = (x3 > 0.f) ? x3 : 0.2f * x3;
        float w0 = __expf(x0), w1 = __expf(x1), w2 = __expf(x2), w3 = __expf(x3);
        union { uint4 u; __half2 h2[4]; } r0, r1, r2, r3;
        r0.u = *reinterpret_cast<const uint4*>(fq + (size_t)s0 * F);
        r1.u = *reinterpret_cast<const uint4*>(fq + (size_t)s1 * F);
        r2.u = *reinterpret_cast<const uint4*>(fq + (size_t)s2 * F);
        r3.u = *reinterpret_cast<const uint4*>(fq + (size_t)s3 * F);
        dsum += (w0 + w1) + (w2 + w3);
#pragma unroll
        for (int k = 0; k < 4; ++k) {
            float2 f0 = __half22float2(r0.h2[k]);
            float2 f1 = __half22float2(r1.h2[k]);
            float2 f2 = __half22float2(r2.h2[k]);
            float2 f3 = __half22float2(r3.h2[k]);
            acc[2 * k]     += w0 * f0.x + w1 * f1.x + w2 * f2.x + w3 * f3.x;
            acc[2 * k + 1] += w0 * f0.y + w1 * f1.y + w2 * f2.y + w3 * f3.y;
        }
    }
    for (; i < re; ++i) {
        int s = esrc[i];
        float x = el[(size_t)s * H + h] + ern;
        x = (x > 0.f) ? x : 0.2f * x;
        float w = __expf(x);
        union { uint4 u; __half2 h2[4]; } r;
        r.u = *reinterpret_cast<const uint4*>(fq + (size_t)s * F);
        dsum += w;
#pragma unroll
        for (int k = 0; k < 4; ++k) {
            float2 f = __half22float2(r.h2[k]);
            acc[2 * k]     += w * f.x;
            acc[2 * k + 1] += w * f.y;
        }
    }
    float inv = (re > rs) ? 1.f / dsum : 0.f;
    float4 b0 = *reinterpret_cast<const float4*>(bias + col);
    float4 b1 = *reinterpret_cast<const float4*>(bias + col + 4);
    float o[8] = {acc[0] * inv + b0.x, acc[1] * inv + b0.y,
                  acc[2] * inv + b0.z, acc[3] * inv + b0.w,
                  acc[4] * inv + b1.x, acc[5] * inv + b1.y,
                  acc[6] * inv + b1.z, acc[7] * inv + b1.w};
    if constexpr (HOUT) {
        union { __half2 h2[4]; uint4 u; } pk;
        pk.h2[0] = __floats2half2_rn(o[0], o[1]);
        pk.h2[1] = __floats2half2_rn(o[2], o[3]);
        pk.h2[2] = __floats2half2_rn(o[4], o[5]);
        pk.h2[3] = __floats2half2_rn(o[6], o[7]);
        *reinterpret_cast<uint4*>((__half*)rst_ + (size_t)n * F + col) = pk.u;
    } else {
        float* op = (float*)rst_ + (size_t)n * F + col;
        *reinterpret_cast<float4*>(op)     = make_float4(o[0], o[1], o[2], o[3]);
        *reinterpret_cast<float4*>(op + 4) = make_float4(o[4], o[5], o[6], o[7]);
    }
}

// ---------- per-graph mean pooling (sorted gid -> segmented reduce) --------
__global__ __launch_bounds__(1024) void seg_pool_kernel(
        const float* __restrict__ h, const int* __restrict__ start,
        float* __restrict__ out, int D) {
    __shared__ float part[7][128];
    int g = blockIdx.x;
    int d = threadIdx.x & 127;
    int j = threadIdx.x >> 7;           // 0..7
    int s = start[g], e = start[g + 1];
    float acc = 0.f;
    for (int n = s + j; n < e; n += 8) acc += h[(size_t)n * D + d];
    if (j > 0) part[j - 1][d] = acc;
    __syncthreads();
    if (j == 0) {
#pragma unroll
        for (int k = 0; k < 7; ++k) acc += part[k][d];
        out[(size_t)g * D + d] = acc / fmaxf((float)(e - s), 1.f);
    }
}

extern "C" void kernel_launch(void* const* d_in, const int* in_sizes, int n_in,
                              void* d_out, int out_size, void* d_ws, size_t ws_size,
                              hipStream_t stream) {
    const float* x   = (const float*)d_in[0];
    const float* W1  = (const float*)d_in[1];
    const float* al1 = (const float*)d_in[2];
    const float* ar1 = (const float*)d_in[3];
    const float* b1  = (const float*)d_in[4];
    const float* W2  = (const float*)d_in[5];
    const float* al2 = (const float*)d_in[6];
    const float* ar2 = (const float*)d_in[7];
    const float* b2  = (const float*)d_in[8];
    const int* src   = (const int*)d_in[9];
    const int* dst   = (const int*)d_in[10];
    const int* gid   = (const int*)d_in[11];
    float* out = (float*)d_out;

    float* ws = (float*)d_ws;
    size_t off = 0;
    int* deg    = (int*)(ws + off); off += N_NODES;     // zeroed via memset
    int* cursor = (int*)(ws + off); off += N_NODES;     // zeroed via memset
    int* rowptr = (int*)(ws + off); off += N_NODES + 4;
    int* gstart = (int*)(ws + off); off += N_GRAPHS + 4;
    int* esrc   = (int*)(ws + off); off += N_EDGES;
    __half* w1t    = (__half*)(ws + off); off += 512 * 256 / 2;
    __half* w2t    = (__half*)(ws + off); off += 128 * 512 / 2;
    __half* feat1h = (__half*)(ws + off); off += (size_t)N_NODES * 256;   // 512 halves
    float*  el1    = ws + off; off += (size_t)N_NODES * 8;
    float*  er1    = ws + off; off += (size_t)N_NODES * 8;
    __half* rst1h  = (__half*)(ws + off); off += (size_t)N_NODES * 256;   // 512 halves
    __half* feat2h = (__half*)(ws + off); off += (size_t)N_NODES * 64;    // 128 halves
    float*  el2    = ws + off; off += N_NODES;
    float*  er2    = ws + off; off += N_NODES;
    float*  rst2   = ws + off; off += (size_t)N_NODES * 128;

    // deg + cursor zero (contiguous) via memset node — no kernel launch
    hipMemsetAsync(deg, 0, sizeof(int) * 2 * N_NODES, stream);

    // setup (transposes + gstart) + degree histogram, one launch
    setup_hist<<<(N_EDGES + 255) / 256, 256, 0, stream>>>(
        W1, W2, w1t, w2t, gid, gstart, dst, deg);
    scan_kernel<<<1, 1024, 0, stream>>>(deg, rowptr, N_NODES);

    // ===== layer 1 GEMM (f32 A converted in staging) ∥ CSR scatter =====
    const int g1rows = (N_NODES + 127) / 128;            // 157
    const int g1nb   = g1rows * (512 / 128);             // 628
    const int scb    = (N_EDGES + 255) / 256;            // 1250
    gemm_scatter_kernel<128, 128, 64, 64, 8, 64, true><<<g1nb + scb, 256, 0, stream>>>(
        x, w1t, feat1h, al1, ar1, el1, er1, N_NODES, 512, 256, g1rows,
        src, dst, rowptr, cursor, esrc);
    node_aggr_wave<512, 8, true><<<(N_NODES * 64 + 255) / 256, 256, 0, stream>>>(
        feat1h, el1, er1, rowptr, esrc, b1, rst1h, N_NODES);

    // ===== layer 2: H=1, D=128; WN==D -> plain el/er stores =====
    dim3 g2((N_NODES + 63) / 64, 1);
    gemm_kernel<64, 128, 16, 128, 1, 128, false><<<g2, 256, 0, stream>>>(
        rst1h, w2t, feat2h, al2, ar2, el2, er2, N_NODES, 128, 512);
    node_aggr_wave<128, 1, false><<<(N_NODES * 16 + 255) / 256, 256, 0, stream>>>(
        feat2h, el2, er2, rowptr, esrc, b2, rst2, N_NODES);

    // ===== readout: per-graph mean (segmented, no atomics) =====
    seg_pool_kernel<<<N_GRAPHS, 1024, 0, stream>>>(rst2, gstart, out, 128);
}

// Round 16
// 176.417 us; speedup vs baseline: 2.8961x; 1.0305x over previous
//
#include <hip/hip_runtime.h>
#include <hip/hip_fp16.h>

#define N_NODES  20000
#define N_EDGES  320000
#define N_GRAPHS 128

typedef _Float16 half8 __attribute__((ext_vector_type(8)));
typedef float    f32x4 __attribute__((ext_vector_type(4)));

// ---------- setup (transposes + gstart) + degree histogram, one launch ----
__global__ void setup_hist(const float* __restrict__ W1, const float* __restrict__ W2,
                           __half* __restrict__ w1t, __half* __restrict__ w2t,
                           const int* __restrict__ gid, int* __restrict__ gstart,
                           const int* __restrict__ dst, int* __restrict__ deg) {
    const int tid  = blockIdx.x * blockDim.x + threadIdx.x;
    const int nthr = gridDim.x * blockDim.x;
    for (int i = tid; i < 256 * 512; i += nthr) {
        int r = i >> 9, c = i & 511;
        w1t[c * 256 + r] = __float2half(W1[i]);
    }
    for (int i = tid; i < 512 * 128; i += nthr) {
        int r = i >> 7, c = i & 127;
        w2t[c * 512 + r] = __float2half(W2[i]);
    }
    if (tid <= N_GRAPHS) {
        if (tid == N_GRAPHS) gstart[N_GRAPHS] = N_NODES;
        else {
            int lo = 0, hi = N_NODES;
            while (lo < hi) {
                int mid = (lo + hi) >> 1;
                if (gid[mid] < tid) lo = mid + 1; else hi = mid;
            }
            gstart[tid] = lo;
        }
    }
    for (int e = tid; e < N_EDGES; e += nthr) atomicAdd(&deg[dst[e]], 1);
}

// ---------- single-block exclusive scan deg -> rowptr ----------
__global__ void scan_kernel(const int* __restrict__ deg, int* __restrict__ rowptr, int n) {
    __shared__ int partial[1024];
    const int t = threadIdx.x;
    const int CH = (n + 1023) / 1024;
    const int base = t * CH;
    int local = 0;
    for (int i = 0; i < CH; ++i)
        if (base + i < n) local += deg[base + i];
    partial[t] = local;
    __syncthreads();
    for (int o = 1; o < 1024; o <<= 1) {
        int v = (t >= o) ? partial[t - o] : 0;
        __syncthreads();
        partial[t] += v;
        __syncthreads();
    }
    int run = (t == 0) ? 0 : partial[t - 1];
    for (int i = 0; i < CH; ++i) {
        if (base + i <= n) rowptr[base + i] = run;
        if (base + i < n) run += deg[base + i];
    }
}

// ---------- MFMA fp16 GEMM + fused el/er (device body) ----------
template <int BM, int BN, int WM, int WN, int H, int D, bool AF32>
__device__ __forceinline__ void gemm_body(
        int bx, int by,
        const void* __restrict__ A_, const __half* __restrict__ BT,
        __half* __restrict__ C, const float* __restrict__ al,
        const float* __restrict__ ar, float* __restrict__ el,
        float* __restrict__ er, int Mm, int Nn, int Kk) {
    constexpr int BK  = 32;
    constexpr int MFR = WM / 16, NFR = WN / 16;
    constexpr int WCOLS = BN / WN;
    __shared__ __align__(16) __half As[BM * BK];
    __shared__ __align__(16) __half Bs[BN * BK];
    const int tid  = threadIdx.x;
    const int w    = tid >> 6, lane = tid & 63;
    const int wr   = w / WCOLS, wc = w % WCOLS;
    const int brow = bx * BM;
    const int bcol = by * BN;
    const int lr   = lane & 15;
    const int lk   = (lane >> 4) * 8;

    f32x4 acc[MFR][NFR] = {};

    for (int k0 = 0; k0 < Kk; k0 += BK) {
        for (int c = tid; c < BM * 4; c += 256) {
            int r = c >> 2, ko = (c & 3) * 8;
            int gr = brow + r; if (gr >= Mm) gr = Mm - 1;
            int off = (r * BK + ko) ^ ((r & 7) << 3);
            if constexpr (AF32) {
                const float* ap = (const float*)A_ + (size_t)gr * Kk + k0 + ko;
                float4 v0 = *reinterpret_cast<const float4*>(ap);
                float4 v1 = *reinterpret_cast<const float4*>(ap + 4);
                union { __half2 h2[4]; uint4 u; } pk;
                pk.h2[0] = __floats2half2_rn(v0.x, v0.y);
                pk.h2[1] = __floats2half2_rn(v0.z, v0.w);
                pk.h2[2] = __floats2half2_rn(v1.x, v1.y);
                pk.h2[3] = __floats2half2_rn(v1.z, v1.w);
                *reinterpret_cast<uint4*>(&As[off]) = pk.u;
            } else {
                *reinterpret_cast<uint4*>(&As[off]) =
                    *reinterpret_cast<const uint4*>((const __half*)A_ + (size_t)gr * Kk + k0 + ko);
            }
        }
        for (int c = tid; c < BN * 4; c += 256) {
            int r = c >> 2, ko = (c & 3) * 8;
            int off = (r * BK + ko) ^ ((r & 7) << 3);
            *reinterpret_cast<uint4*>(&Bs[off]) =
                *reinterpret_cast<const uint4*>(&BT[(size_t)(bcol + r) * Kk + k0 + ko]);
        }
        __syncthreads();
        half8 af[MFR], bf[NFR];
#pragma unroll
        for (int m = 0; m < MFR; ++m) {
            int r = wr * WM + m * 16 + lr;
            af[m] = *reinterpret_cast<const half8*>(&As[(r * BK + lk) ^ ((r & 7) << 3)]);
        }
#pragma unroll
        for (int n = 0; n < NFR; ++n) {
            int r = wc * WN + n * 16 + lr;
            bf[n] = *reinterpret_cast<const half8*>(&Bs[(r * BK + lk) ^ ((r & 7) << 3)]);
        }
#pragma unroll
        for (int m = 0; m < MFR; ++m)
#pragma unroll
            for (int n = 0; n < NFR; ++n)
                acc[m][n] = __builtin_amdgcn_mfma_f32_16x16x32_f16(af[m], bf[n], acc[m][n], 0, 0, 0);
        __syncthreads();
    }

#pragma unroll
    for (int m = 0; m < MFR; ++m) {
        int r0 = brow + wr * WM + m * 16 + ((lane >> 4) << 2);
#pragma unroll
        for (int n = 0; n < NFR; ++n) {
            int cc = bcol + wc * WN + n * 16 + lr;
#pragma unroll
            for (int g = 0; g < 4; ++g)
                if (r0 + g < Mm) C[(size_t)(r0 + g) * Nn + cc] = __float2half(acc[m][n][g]);
        }
    }
    const int h = (bcol + wc * WN) / D;
    float alv[NFR], arv[NFR];
#pragma unroll
    for (int n = 0; n < NFR; ++n) {
        alv[n] = al[bcol + wc * WN + n * 16 + lr];
        arv[n] = ar[bcol + wc * WN + n * 16 + lr];
    }
#pragma unroll
    for (int m = 0; m < MFR; ++m) {
#pragma unroll
        for (int g = 0; g < 4; ++g) {
            float pl = 0.f, pr = 0.f;
#pragma unroll
            for (int n = 0; n < NFR; ++n) {
                pl += acc[m][n][g] * alv[n];
                pr += acc[m][n][g] * arv[n];
            }
            pl += __shfl_xor(pl, 1); pl += __shfl_xor(pl, 2);
            pl += __shfl_xor(pl, 4); pl += __shfl_xor(pl, 8);
            pr += __shfl_xor(pr, 1); pr += __shfl_xor(pr, 2);
            pr += __shfl_xor(pr, 4); pr += __shfl_xor(pr, 8);
            int gr = brow + wr * WM + m * 16 + ((lane >> 4) << 2) + g;
            if (lr == 0 && gr < Mm) {
                if constexpr (WN == D) {
                    el[(size_t)gr * H + h] = pl;
                    er[(size_t)gr * H + h] = pr;
                } else {
                    atomicAdd(&el[(size_t)gr * H + h], pl);
                    atomicAdd(&er[(size_t)gr * H + h], pr);
                }
            }
        }
    }
}

// plain GEMM kernel (layer 2)
template <int BM, int BN, int WM, int WN, int H, int D, bool AF32>
__global__ __launch_bounds__(256) void gemm_kernel(
        const void* __restrict__ A_, const __half* __restrict__ BT,
        __half* __restrict__ C, const float* __restrict__ al,
        const float* __restrict__ ar, float* __restrict__ el,
        float* __restrict__ er, int Mm, int Nn, int Kk) {
    gemm_body<BM, BN, WM, WN, H, D, AF32>(blockIdx.x, blockIdx.y, A_, BT, C,
                                          al, ar, el, er, Mm, Nn, Kk);
}

// fused GEMM (layer 1) + CSR scatter, XCD-affine swizzle:
// GEMM block ids are laid out so all NCOL column-blocks of one row-panel
// share bid%8 -> same XCD under round-robin dispatch -> A panel is fetched
// into that XCD's L2 once instead of NCOL times (2.56 MB/XCD, fits 4 MB).
template <int BM, int BN, int WM, int WN, int H, int D, bool AF32, int NCOL>
__global__ __launch_bounds__(256) void gemm_scatter_kernel(
        const void* __restrict__ A_, const __half* __restrict__ BT,
        __half* __restrict__ C, const float* __restrict__ al,
        const float* __restrict__ ar, float* __restrict__ el,
        float* __restrict__ er, int Mm, int Nn, int Kk, int gemmRows,
        const int* __restrict__ src, const int* __restrict__ dst,
        const int* __restrict__ rowptr, int* __restrict__ cursor,
        int* __restrict__ esrc) {
    const int rowsPad = ((gemmRows + 7) >> 3) << 3;
    const int nbGemm  = rowsPad * NCOL;
    const int bid = blockIdx.x;
    if (bid < nbGemm) {
        int slot = bid & 7;                 // intended XCD
        int c    = (bid >> 3) % NCOL;       // column block
        int grp  = bid / (8 * NCOL);        // row group
        int r    = grp * 8 + slot;
        if (r < gemmRows)
            gemm_body<BM, BN, WM, WN, H, D, AF32>(r, c, A_, BT, C,
                                                  al, ar, el, er, Mm, Nn, Kk);
    } else {
        int e = (bid - nbGemm) * blockDim.x + threadIdx.x;
        if (e < N_EDGES) {
            int d = dst[e];
            int pos = rowptr[d] + atomicAdd(&cursor[d], 1);
            esrc[pos] = src[e];
        }
    }
}

// ---------- per-node aggregation: wave-per-node, inline edge weights -------
template <int F, int H, bool HOUT>
__global__ __launch_bounds__(256) void node_aggr_wave(
        const __half* __restrict__ feat, const float* __restrict__ el,
        const float* __restrict__ er, const int* __restrict__ rowptr,
        const int* __restrict__ esrc, const float* __restrict__ bias,
        void* __restrict__ rst_, int N) {
    constexpr int LPN = F / 8;
    constexpr int NPW = 64 / LPN;
    constexpr int D   = F / H;
    const int wid  = (blockIdx.x * blockDim.x + threadIdx.x) >> 6;
    const int lane = threadIdx.x & 63;
    const int n    = wid * NPW + lane / LPN;
    if (n >= N) return;
    const int col = (lane % LPN) * 8;
    const int h   = col / D;
    const float ern = er[(size_t)n * H + h];
    const int rs = rowptr[n], re = rowptr[n + 1];
    const __half* fq = feat + col;

    float acc[8] = {};
    float dsum = 0.f;
    int i = rs;
    for (; i + 4 <= re; i += 4) {
        int s0 = esrc[i], s1 = esrc[i + 1], s2 = esrc[i + 2], s3 = esrc[i + 3];
        float x0 = el[(size_t)s0 * H + h] + ern;
        float x1 = el[(size_t)s1 * H + h] + ern;
        float x2 = el[(size_t)s2 * H + h] + ern;
        float x3 = el[(size_t)s3 * H + h] + ern;
        x0 = (x0 > 0.f) ? x0 : 0.2f * x0;
        x1 = (x1 > 0.f) ? x1 : 0.2f * x1;
        x2 = (x2 > 0.f) ? x2 : 0.2f * x2;
        x3 = (x3 > 0.f) ? x3 : 0.2f * x3;
        float w0 = __expf(x0), w1 = __expf(x1), w2 = __expf(x2), w3 = __expf(x3);
        union { uint4 u; __half2 h2[4]; } r0, r1, r2, r3;
        r0.u = *reinterpret_cast<const uint4*>(fq + (size_t)s0 * F);
        r1.u = *reinterpret_cast<const uint4*>(fq + (size_t)s1 * F);
        r2.u = *reinterpret_cast<const uint4*>(fq + (size_t)s2 * F);
        r3.u = *reinterpret_cast<const uint4*>(fq + (size_t)s3 * F);
        dsum += (w0 + w1) + (w2 + w3);
#pragma unroll
        for (int k = 0; k < 4; ++k) {
            float2 f0 = __half22float2(r0.h2[k]);
            float2 f1 = __half22float2(r1.h2[k]);
            float2 f2 = __half22float2(r2.h2[k]);
            float2 f3 = __half22float2(r3.h2[k]);
            acc[2 * k]     += w0 * f0.x + w1 * f1.x + w2 * f2.x + w3 * f3.x;
            acc[2 * k + 1] += w0 * f0.y + w1 * f1.y + w2 * f2.y + w3 * f3.y;
        }
    }
    for (; i < re; ++i) {
        int s = esrc[i];
        float x = el[(size_t)s * H + h] + ern;
        x = (x > 0.f) ? x : 0.2f * x;
        float w = __expf(x);
        union { uint4 u; __half2 h2[4]; } r;
        r.u = *reinterpret_cast<const uint4*>(fq + (size_t)s * F);
        dsum += w;
#pragma unroll
        for (int k = 0; k < 4; ++k) {
            float2 f = __half22float2(r.h2[k]);
            acc[2 * k]     += w * f.x;
            acc[2 * k + 1] += w * f.y;
        }
    }
    float inv = (re > rs) ? 1.f / dsum : 0.f;
    float4 b0 = *reinterpret_cast<const float4*>(bias + col);
    float4 b1 = *reinterpret_cast<const float4*>(bias + col + 4);
    float o[8] = {acc[0] * inv + b0.x, acc[1] * inv + b0.y,
                  acc[2] * inv + b0.z, acc[3] * inv + b0.w,
                  acc[4] * inv + b1.x, acc[5] * inv + b1.y,
                  acc[6] * inv + b1.z, acc[7] * inv + b1.w};
    if constexpr (HOUT) {
        union { __half2 h2[4]; uint4 u; } pk;
        pk.h2[0] = __floats2half2_rn(o[0], o[1]);
        pk.h2[1] = __floats2half2_rn(o[2], o[3]);
        pk.h2[2] = __floats2half2_rn(o[4], o[5]);
        pk.h2[3] = __floats2half2_rn(o[6], o[7]);
        *reinterpret_cast<uint4*>((__half*)rst_ + (size_t)n * F + col) = pk.u;
    } else {
        float* op = (float*)rst_ + (size_t)n * F + col;
        *reinterpret_cast<float4*>(op)     = make_float4(o[0], o[1], o[2], o[3]);
        *reinterpret_cast<float4*>(op + 4) = make_float4(o[4], o[5], o[6], o[7]);
    }
}

// ---------- per-graph mean pooling (sorted gid; fp16 input) ----------------
__global__ __launch_bounds__(1024) void seg_pool_kernel(
        const __half* __restrict__ h, const int* __restrict__ start,
        float* __restrict__ out, int D) {
    __shared__ float part[7][128];
    int g = blockIdx.x;
    int d = threadIdx.x & 127;
    int j = threadIdx.x >> 7;           // 0..7
    int s = start[g], e = start[g + 1];
    float acc = 0.f;
    for (int n = s + j; n < e; n += 8) acc += __half2float(h[(size_t)n * D + d]);
    if (j > 0) part[j - 1][d] = acc;
    __syncthreads();
    if (j == 0) {
#pragma unroll
        for (int k = 0; k < 7; ++k) acc += part[k][d];
        out[(size_t)g * D + d] = acc / fmaxf((float)(e - s), 1.f);
    }
}

extern "C" void kernel_launch(void* const* d_in, const int* in_sizes, int n_in,
                              void* d_out, int out_size, void* d_ws, size_t ws_size,
                              hipStream_t stream) {
    const float* x   = (const float*)d_in[0];
    const float* W1  = (const float*)d_in[1];
    const float* al1 = (const float*)d_in[2];
    const float* ar1 = (const float*)d_in[3];
    const float* b1  = (const float*)d_in[4];
    const float* W2  = (const float*)d_in[5];
    const float* al2 = (const float*)d_in[6];
    const float* ar2 = (const float*)d_in[7];
    const float* b2  = (const float*)d_in[8];
    const int* src   = (const int*)d_in[9];
    const int* dst   = (const int*)d_in[10];
    const int* gid   = (const int*)d_in[11];
    float* out = (float*)d_out;

    float* ws = (float*)d_ws;
    size_t off = 0;
    int* deg    = (int*)(ws + off); off += N_NODES;     // zeroed via memset
    int* cursor = (int*)(ws + off); off += N_NODES;     // zeroed via memset
    int* rowptr = (int*)(ws + off); off += N_NODES + 4;
    int* gstart = (int*)(ws + off); off += N_GRAPHS + 4;
    int* esrc   = (int*)(ws + off); off += N_EDGES;
    __half* w1t    = (__half*)(ws + off); off += 512 * 256 / 2;
    __half* w2t    = (__half*)(ws + off); off += 128 * 512 / 2;
    __half* feat1h = (__half*)(ws + off); off += (size_t)N_NODES * 256;   // 512 halves
    float*  el1    = ws + off; off += (size_t)N_NODES * 8;
    float*  er1    = ws + off; off += (size_t)N_NODES * 8;
    __half* rst1h  = (__half*)(ws + off); off += (size_t)N_NODES * 256;   // 512 halves
    __half* feat2h = (__half*)(ws + off); off += (size_t)N_NODES * 64;    // 128 halves
    float*  el2    = ws + off; off += N_NODES;
    float*  er2    = ws + off; off += N_NODES;
    __half* rst2h  = (__half*)(ws + off); off += (size_t)N_NODES * 64;    // 128 halves

    // deg + cursor zero (contiguous) via memset node — no kernel launch
    hipMemsetAsync(deg, 0, sizeof(int) * 2 * N_NODES, stream);

    // setup (transposes + gstart) + degree histogram, one launch
    setup_hist<<<(N_EDGES + 255) / 256, 256, 0, stream>>>(
        W1, W2, w1t, w2t, gid, gstart, dst, deg);
    scan_kernel<<<1, 1024, 0, stream>>>(deg, rowptr, N_NODES);

    // ===== layer 1 GEMM (XCD-affine swizzle) ∥ CSR scatter =====
    const int g1rows   = (N_NODES + 127) / 128;          // 157
    const int rowsPad  = ((g1rows + 7) / 8) * 8;         // 160
    const int g1nb     = rowsPad * 4;                    // 640 (incl. 12 idle)
    const int scb      = (N_EDGES + 255) / 256;          // 1250
    gemm_scatter_kernel<128, 128, 64, 64, 8, 64, true, 4><<<g1nb + scb, 256, 0, stream>>>(
        x, w1t, feat1h, al1, ar1, el1, er1, N_NODES, 512, 256, g1rows,
        src, dst, rowptr, cursor, esrc);
    node_aggr_wave<512, 8, true><<<(N_NODES * 64 + 255) / 256, 256, 0, stream>>>(
        feat1h, el1, er1, rowptr, esrc, b1, rst1h, N_NODES);

    // ===== layer 2: H=1, D=128; WN==D -> plain el/er stores =====
    dim3 g2((N_NODES + 63) / 64, 1);
    gemm_kernel<64, 128, 16, 128, 1, 128, false><<<g2, 256, 0, stream>>>(
        rst1h, w2t, feat2h, al2, ar2, el2, er2, N_NODES, 128, 512);
    node_aggr_wave<128, 1, true><<<(N_NODES * 16 + 255) / 256, 256, 0, stream>>>(
        feat2h, el2, er2, rowptr, esrc, b2, rst2h, N_NODES);

    // ===== readout: per-graph mean (segmented, fp16 input) =====
    seg_pool_kernel<<<N_GRAPHS, 1024, 0, stream>>>(rst2h, gstart, out, 128);
}